// Round 2
// baseline (943.783 us; speedup 1.0000x reference)
//
#include <hip/hip_runtime.h>
#include <hip/hip_bf16.h>
#include <math.h>

// Problem constants (from reference): N=524288, D=64, H=128, E=8, A=18
#define DD 64
#define HH 128
#define EE 8
#define AA 18
#define BN_EPS 1e-5f

// Near-tie margin: f32 logit worst-case error ~5e-5; 20x safety.
#define TIE_MARGIN 1e-3f

// Per-expert LDS stride: 18*64=1152 floats, +4 pad so 1156 % 32 == 4 →
// each expert e maps its columns to bank offset 4e (all 8 distinct) →
// conflict-free ds_read_b128 across divergent expert indices.
#define WE_STRIDE 1156

__global__ __launch_bounds__(256, 4) void moe_router_kernel(
    const float* __restrict__ X,
    const float* __restrict__ W1,
    const float* __restrict__ b1,
    const float* __restrict__ gamma,
    const float* __restrict__ beta,
    const float* __restrict__ rmean,
    const float* __restrict__ rvar,
    const float* __restrict__ W2,
    const float* __restrict__ b2,
    const float* __restrict__ We,
    float* __restrict__ out,      // [N, AA]
    float* __restrict__ ret,      // [N, EE]
    int Ntot)
{
    __shared__ float sWe[EE * WE_STRIDE];

    const int tid = threadIdx.x;
    const int n = blockIdx.x * 256 + tid;

    // Stage We into LDS (coalesced read, padded write).
    for (int i = tid; i < EE * AA * DD; i += 256) {
        int e = i / (AA * DD);
        int r = i - e * (AA * DD);
        sWe[e * WE_STRIDE + r] = We[i];
    }

    // Load this thread's X row into registers early (overlaps staging).
    float4 x[16];
    if (n < Ntot) {
        const float4* xv = (const float4*)(X + (size_t)n * DD);
        #pragma unroll
        for (int k = 0; k < 16; ++k) x[k] = xv[k];
    }

    __syncthreads();

    if (n >= Ntot) return;

    // ---- h = relu(BN(X @ W1^T + b1)); logits = h @ W2^T + b2 (f32) ----
    float logits[EE];
    #pragma unroll
    for (int e = 0; e < EE; ++e) logits[e] = b2[e];

    #pragma unroll 2
    for (int j = 0; j < HH; ++j) {
        const float4* wv = (const float4*)(W1 + j * DD);  // uniform -> s_load
        float s0 = 0.f, s1 = 0.f, s2 = 0.f, s3 = 0.f;
        #pragma unroll
        for (int k = 0; k < 16; ++k) {
            float4 w = wv[k];
            s0 = fmaf(x[k].x, w.x, s0);
            s1 = fmaf(x[k].y, w.y, s1);
            s2 = fmaf(x[k].z, w.z, s2);
            s3 = fmaf(x[k].w, w.w, s3);
        }
        float h = ((s0 + s1) + (s2 + s3)) + b1[j];
        float sc = gamma[j] * rsqrtf(rvar[j] + BN_EPS);
        float hb = fmaf(h - rmean[j], sc, beta[j]);
        hb = fmaxf(hb, 0.f);
        #pragma unroll
        for (int e = 0; e < EE; ++e)
            logits[e] = fmaf(hb, W2[e * HH + j], logits[e]);  // uniform W2 -> s_load
    }

    // ---- f32 argmax (first index wins, matches np argmax) ----
    int emax = 0;
    float lmax = logits[0];
    #pragma unroll
    for (int e = 1; e < EE; ++e) {
        if (logits[e] > lmax) { lmax = logits[e]; emax = e; }
    }
    float second = -INFINITY;
    #pragma unroll
    for (int e = 0; e < EE; ++e) {
        if (e != emax && logits[e] > second) second = logits[e];
    }

    // ---- near-tie: redo logits in f64 so our argmax matches the true
    // (reference) argmax. Rare (<~1% of rows), cold path. ----
    if (lmax - second < TIE_MARGIN) {
        double ld[EE];
        #pragma unroll
        for (int e = 0; e < EE; ++e) ld[e] = (double)b2[e];
        const float* xs = (const float*)x;  // statically indexed below
        for (int j = 0; j < HH; ++j) {
            const float* w = W1 + j * DD;
            double hd = 0.0;
            #pragma unroll
            for (int k = 0; k < DD; ++k)
                hd += (double)xs[k] * (double)w[k];
            hd += (double)b1[j];
            double sc = (double)gamma[j] / sqrt((double)rvar[j] + 1e-5);
            double hb = (hd - (double)rmean[j]) * sc + (double)beta[j];
            hb = hb > 0.0 ? hb : 0.0;
            #pragma unroll
            for (int e = 0; e < EE; ++e)
                ld[e] += hb * (double)W2[e * HH + j];
        }
        emax = 0;
        double lm = ld[0];
        #pragma unroll
        for (int e = 1; e < EE; ++e) {
            if (ld[e] > lm) { lm = ld[e]; emax = e; }
        }
    }

    // ---- ret = y_hard - sg(y_soft) + y_soft == one_hot (exact off-argmax) ----
    float rv[EE];
    #pragma unroll
    for (int e = 0; e < EE; ++e) rv[e] = (e == emax) ? 1.0f : 0.0f;
    float4* retv = (float4*)(ret + (size_t)n * EE);
    retv[0] = make_float4(rv[0], rv[1], rv[2], rv[3]);
    retv[1] = make_float4(rv[4], rv[5], rv[6], rv[7]);

    // ---- output[a] = dot(X_row, We[emax][a][:]) ----
    const float* wexp = &sWe[emax * WE_STRIDE];
    float outv[AA];
    #pragma unroll
    for (int a = 0; a < AA; ++a) {
        const float4* wv = (const float4*)(wexp + a * DD);  // 16B-aligned LDS
        float s0 = 0.f, s1 = 0.f, s2 = 0.f, s3 = 0.f;
        #pragma unroll
        for (int k = 0; k < 16; ++k) {
            float4 w = wv[k];
            s0 = fmaf(x[k].x, w.x, s0);
            s1 = fmaf(x[k].y, w.y, s1);
            s2 = fmaf(x[k].z, w.z, s2);
            s3 = fmaf(x[k].w, w.w, s3);
        }
        outv[a] = (s0 + s1) + (s2 + s3);
    }
    float2* ov = (float2*)(out + (size_t)n * AA);  // 18*4B = 72B stride, 8B-aligned
    #pragma unroll
    for (int a2 = 0; a2 < 9; ++a2)
        ov[a2] = make_float2(outv[2 * a2], outv[2 * a2 + 1]);
}

extern "C" void kernel_launch(void* const* d_in, const int* in_sizes, int n_in,
                              void* d_out, int out_size, void* d_ws, size_t ws_size,
                              hipStream_t stream) {
    const float* X     = (const float*)d_in[0];
    const float* W1    = (const float*)d_in[1];
    const float* b1    = (const float*)d_in[2];
    const float* gamma = (const float*)d_in[3];
    const float* beta  = (const float*)d_in[4];
    const float* rmean = (const float*)d_in[5];
    const float* rvar  = (const float*)d_in[6];
    const float* W2    = (const float*)d_in[7];
    const float* b2    = (const float*)d_in[8];
    const float* We    = (const float*)d_in[9];

    const int Ntot = in_sizes[0] / DD;          // 524288
    float* out = (float*)d_out;                 // [N, AA] first
    float* ret = out + (size_t)Ntot * AA;       // then [N, EE]

    const int nblocks = (Ntot + 255) / 256;     // 2048
    moe_router_kernel<<<nblocks, 256, 0, stream>>>(
        X, W1, b1, gamma, beta, rmean, rvar, W2, b2, We, out, ret, Ntot);
}

// Round 4
// 780.853 us; speedup vs baseline: 1.2087x; 1.2087x over previous
//
#include <hip/hip_runtime.h>
#include <hip/hip_bf16.h>
#include <math.h>

// Problem constants (from reference): N=524288, D=64, H=128, E=8, A=18
#define DD 64
#define HH 128
#define EE 8
#define AA 18
#define BN_EPS 1e-5f

// Near-tie margin: realistic f32 logit error ~3e-7 rms (worst ~1e-6);
// 5e-5 is ~170x safety while keeping the f64 slow path to ~0.05% of rows
// (~3% of waves with exec-masked lanes).
#define TIE_MARGIN 5e-5f

// Per-expert LDS stride: 18*64=1152 floats, +4 pad so 1156 % 32 == 4 →
// each expert e maps its columns to bank offset 4e (all 8 distinct) →
// conflict-free ds_read_b128 across divergent expert indices.
#define WE_STRIDE 1156

__global__ __launch_bounds__(256, 4) void moe_router_kernel(
    const float* __restrict__ X,
    const float* __restrict__ W1,
    const float* __restrict__ b1,
    const float* __restrict__ gamma,
    const float* __restrict__ beta,
    const float* __restrict__ rmean,
    const float* __restrict__ rvar,
    const float* __restrict__ W2,
    const float* __restrict__ b2,
    const float* __restrict__ We,
    float* __restrict__ out,      // [N, AA]
    float* __restrict__ ret,      // [N, EE]
    int Ntot)
{
    __shared__ float sWe[EE * WE_STRIDE];

    const int tid = threadIdx.x;
    const int n = blockIdx.x * 256 + tid;

    // Stage We into LDS (coalesced read, padded write).
    for (int i = tid; i < EE * AA * DD; i += 256) {
        int e = i / (AA * DD);
        int r = i - e * (AA * DD);
        sWe[e * WE_STRIDE + r] = We[i];
    }

    // Load this thread's X row into registers early (overlaps staging).
    // NOTE: x[] must remain SSA (no address taken, static indices only),
    // otherwise it spills to scratch (134 MB of extra traffic — R2 lesson).
    float4 x[16];
    if (n < Ntot) {
        const float4* xv = (const float4*)(X + (size_t)n * DD);
        #pragma unroll
        for (int k = 0; k < 16; ++k) x[k] = xv[k];
    }

    __syncthreads();

    if (n >= Ntot) return;

    // ---- h = relu(BN(X @ W1^T + b1)); logits = h @ W2^T + b2 (f32) ----
    float logits[EE];
    #pragma unroll
    for (int e = 0; e < EE; ++e) logits[e] = b2[e];

    #pragma unroll 2
    for (int j = 0; j < HH; ++j) {
        const float4* wv = (const float4*)(W1 + j * DD);  // uniform -> s_load
        float s0 = 0.f, s1 = 0.f, s2 = 0.f, s3 = 0.f;
        #pragma unroll
        for (int k = 0; k < 16; ++k) {
            float4 w = wv[k];
            s0 = fmaf(x[k].x, w.x, s0);
            s1 = fmaf(x[k].y, w.y, s1);
            s2 = fmaf(x[k].z, w.z, s2);
            s3 = fmaf(x[k].w, w.w, s3);
        }
        float h = ((s0 + s1) + (s2 + s3)) + b1[j];
        float sc = gamma[j] * rsqrtf(rvar[j] + BN_EPS);
        float hb = fmaf(h - rmean[j], sc, beta[j]);
        hb = fmaxf(hb, 0.f);
        #pragma unroll
        for (int e = 0; e < EE; ++e)
            logits[e] = fmaf(hb, W2[e * HH + j], logits[e]);  // uniform -> s_load
    }

    // ---- f32 argmax (first index wins, matches np argmax) ----
    int emax = 0;
    float lmax = logits[0];
    #pragma unroll
    for (int e = 1; e < EE; ++e) {
        if (logits[e] > lmax) { lmax = logits[e]; emax = e; }
    }
    float second = -INFINITY;
    #pragma unroll
    for (int e = 0; e < EE; ++e) {
        if (e != emax && logits[e] > second) second = logits[e];
    }

    // ---- near-tie cold path: redo logits in f64 so argmax matches the
    // reference's f64 argmax. X re-read from GLOBAL (L2-hit) so the hot
    // x[] registers are never address-taken. ~0.05% of rows. ----
    if (lmax - second < TIE_MARGIN) {
        const float* xg = X + (size_t)n * DD;
        double ld[EE];
        #pragma unroll
        for (int e = 0; e < EE; ++e) ld[e] = (double)b2[e];
        for (int j = 0; j < HH; ++j) {
            const float* w = W1 + j * DD;
            double hd = 0.0;
            for (int k = 0; k < DD; ++k)
                hd += (double)xg[k] * (double)w[k];
            hd += (double)b1[j];
            double sc = (double)gamma[j] / sqrt((double)rvar[j] + 1e-5);
            double hb = (hd - (double)rmean[j]) * sc + (double)beta[j];
            hb = hb > 0.0 ? hb : 0.0;
            #pragma unroll
            for (int e = 0; e < EE; ++e)
                ld[e] += hb * (double)W2[e * HH + j];
        }
        emax = 0;
        double lm = ld[0];
        #pragma unroll
        for (int e = 1; e < EE; ++e) {
            if (ld[e] > lm) { lm = ld[e]; emax = e; }
        }
    }

    // ---- ret = y_hard - sg(y_soft) + y_soft == one_hot (exact off-argmax) ----
    float4* retv = (float4*)(ret + (size_t)n * EE);
    retv[0] = make_float4(emax == 0 ? 1.f : 0.f, emax == 1 ? 1.f : 0.f,
                          emax == 2 ? 1.f : 0.f, emax == 3 ? 1.f : 0.f);
    retv[1] = make_float4(emax == 4 ? 1.f : 0.f, emax == 5 ? 1.f : 0.f,
                          emax == 6 ? 1.f : 0.f, emax == 7 ? 1.f : 0.f);

    // ---- output[a] = dot(X_row, We[emax][a][:]) ----
    const float* wexp = &sWe[emax * WE_STRIDE];
    float outv[AA];
    #pragma unroll
    for (int a = 0; a < AA; ++a) {
        const float4* wv = (const float4*)(wexp + a * DD);  // 16B-aligned LDS
        float s0 = 0.f, s1 = 0.f, s2 = 0.f, s3 = 0.f;
        #pragma unroll
        for (int k = 0; k < 16; ++k) {
            float4 w = wv[k];
            s0 = fmaf(x[k].x, w.x, s0);
            s1 = fmaf(x[k].y, w.y, s1);
            s2 = fmaf(x[k].z, w.z, s2);
            s3 = fmaf(x[k].w, w.w, s3);
        }
        outv[a] = (s0 + s1) + (s2 + s3);
    }
    float2* ov = (float2*)(out + (size_t)n * AA);  // 72B row stride, 8B-aligned
    #pragma unroll
    for (int a2 = 0; a2 < 9; ++a2)
        ov[a2] = make_float2(outv[2 * a2], outv[2 * a2 + 1]);
}

extern "C" void kernel_launch(void* const* d_in, const int* in_sizes, int n_in,
                              void* d_out, int out_size, void* d_ws, size_t ws_size,
                              hipStream_t stream) {
    const float* X     = (const float*)d_in[0];
    const float* W1    = (const float*)d_in[1];
    const float* b1    = (const float*)d_in[2];
    const float* gamma = (const float*)d_in[3];
    const float* beta  = (const float*)d_in[4];
    const float* rmean = (const float*)d_in[5];
    const float* rvar  = (const float*)d_in[6];
    const float* W2    = (const float*)d_in[7];
    const float* b2    = (const float*)d_in[8];
    const float* We    = (const float*)d_in[9];

    const int Ntot = in_sizes[0] / DD;          // 524288
    float* out = (float*)d_out;                 // [N, AA] first
    float* ret = out + (size_t)Ntot * AA;       // then [N, EE]

    const int nblocks = (Ntot + 255) / 256;     // 2048
    moe_router_kernel<<<nblocks, 256, 0, stream>>>(
        X, W1, b1, gamma, beta, rmean, rvar, W2, b2, We, out, ret, Ntot);
}